// Round 2
// baseline (575.378 us; speedup 1.0000x reference)
//
#include <hip/hip_runtime.h>
#include <math.h>

typedef int vi4 __attribute__((ext_vector_type(4)));

#define WAVES   8
#define THREADS 512
#define WSTRIDE 144   // 128 + 16 pad: keeps 16B alignment, breaks bank alignment

__device__ __forceinline__ float sigmoidf_(float v) {
    return 1.0f / (1.0f + __expf(-v));
}

__global__ __launch_bounds__(THREADS, 4)
void mlgru_kernel(const float* __restrict__ x,
                  const float* __restrict__ hprev,
                  const float* __restrict__ Wf,
                  const float* __restrict__ Wc,
                  const float* __restrict__ Wg,
                  const float* __restrict__ bfp,
                  const float* __restrict__ bcp,
                  const float* __restrict__ bgp,
                  float* __restrict__ out,
                  int nrows)
{
    // wsign[g][j][k] = sign(W_g[j][k]) as int8; j = output col, k = input dim
    __shared__ signed char wsign[3][128][WSTRIDE];   // 54 KB

    const int tid  = threadIdx.x;
    const int lane = tid & 63;
    const int widx = tid >> 6;
    const int m    = lane & 15;   // A-row / C-col within tile
    const int quad = lane >> 4;   // k-chunk / C-row-group

    // ---- stage sign weights into LDS (coalesced float4 reads, g uniform per iter) ----
    #pragma unroll
    for (int it = 0; it < 24; ++it) {
        const int idx = tid + it * THREADS;          // < 3*128*32 = 12288
        const int g   = idx >> 12;
        const int j   = (idx >> 5) & 127;
        const int k4  = idx & 31;
        const float* Wp = (g == 0) ? Wf : ((g == 1) ? Wc : Wg);
        const float4 v = *(const float4*)(Wp + j * 128 + k4 * 4);
        const int b0 = (v.x > 0.f) - (v.x < 0.f);
        const int b1 = (v.y > 0.f) - (v.y < 0.f);
        const int b2 = (v.z > 0.f) - (v.z < 0.f);
        const int b3 = (v.w > 0.f) - (v.w < 0.f);
        *(int*)&wsign[g][j][k4 * 4] =
            (b0 & 0xFF) | ((b1 & 0xFF) << 8) | ((b2 & 0xFF) << 16) | ((b3 & 0xFF) << 24);
    }

    // per-lane biases for col = ct*16 + m, kept in registers across all groups
    float bfv[8], bcv[8], bgv[8];
    #pragma unroll
    for (int ct = 0; ct < 8; ++ct) {
        bfv[ct] = bfp[ct * 16 + m];
        bcv[ct] = bcp[ct * 16 + m];
        bgv[ct] = bgp[ct * 16 + m];
    }
    __syncthreads();

    const int gw   = blockIdx.x * WAVES + widx;
    const int nw   = gridDim.x * WAVES;
    const int ngrp = nrows >> 4;                     // 16 rows per wave-group
    const long long hoff = (long long)nrows * 128;

    for (int grp = gw; grp < ngrp; grp += nw) {
        const int row0 = grp << 4;

        // ---------- quant phase: lane owns row m, k in [16q,16q+16) u [64+16q,+16) ----------
        // (exactly the A-fragment bytes for a0/a1 -> no cross-lane data movement)
        const float* xp = x + (long long)(row0 + m) * 128 + quad * 16;
        float4 xa[8];
        #pragma unroll
        for (int i = 0; i < 4; ++i) xa[i]     = *(const float4*)(xp + 4 * i);
        #pragma unroll
        for (int i = 0; i < 4; ++i) xa[4 + i] = *(const float4*)(xp + 64 + 4 * i);

        float s = 0.f, ss = 0.f;
        #pragma unroll
        for (int i = 0; i < 8; ++i) {
            s  += (xa[i].x + xa[i].y) + (xa[i].z + xa[i].w);
            ss += xa[i].x * xa[i].x + xa[i].y * xa[i].y
                + xa[i].z * xa[i].z + xa[i].w * xa[i].w;
        }
        // reduce across the 4 lanes (quad dim) sharing row m: lane bits 4,5
        s  += __shfl_xor(s, 16);  s  += __shfl_xor(s, 32);
        ss += __shfl_xor(ss, 16); ss += __shfl_xor(ss, 32);
        const float mean = s * (1.0f / 128.0f);
        const float var  = ss * (1.0f / 128.0f) - mean * mean;
        const float rstd = rsqrtf(var + 1e-8f);

        float amax = 0.f;
        #pragma unroll
        for (int i = 0; i < 8; ++i) {
            xa[i].x = (xa[i].x - mean) * rstd;
            xa[i].y = (xa[i].y - mean) * rstd;
            xa[i].z = (xa[i].z - mean) * rstd;
            xa[i].w = (xa[i].w - mean) * rstd;
            amax = fmaxf(amax, fmaxf(fmaxf(fabsf(xa[i].x), fabsf(xa[i].y)),
                                     fmaxf(fabsf(xa[i].z), fabsf(xa[i].w))));
        }
        amax = fmaxf(amax, __shfl_xor(amax, 16));
        amax = fmaxf(amax, __shfl_xor(amax, 32));
        const float sq  = 127.0f / amax;
        const float inv = amax * (1.0f / 127.0f);

        int qw[8];
        #pragma unroll
        for (int i = 0; i < 8; ++i) {
            const float f0 = fminf(fmaxf(rintf(xa[i].x * sq), -128.f), 127.f);
            const float f1 = fminf(fmaxf(rintf(xa[i].y * sq), -128.f), 127.f);
            const float f2 = fminf(fmaxf(rintf(xa[i].z * sq), -128.f), 127.f);
            const float f3 = fminf(fmaxf(rintf(xa[i].w * sq), -128.f), 127.f);
            qw[i] = ((int)f0 & 0xFF) | (((int)f1 & 0xFF) << 8)
                  | (((int)f2 & 0xFF) << 16) | (((int)f3 & 0xFF) << 24);
        }
        const vi4 a0 = { qw[0], qw[1], qw[2], qw[3] };   // k =      quad*16 + [0,16)
        const vi4 a1 = { qw[4], qw[5], qw[6], qw[7] };   // k = 64 + quad*16 + [0,16)

        // inv per C/D output row (row = quad*4 + r); lanes 0..15 hold rows 0..15
        float invr[4];
        #pragma unroll
        for (int r = 0; r < 4; ++r) invr[r] = __shfl(inv, quad * 4 + r);

        // ---------- MFMA over 8 col-tiles x 3 gates, K=128 as 2 chained mfmas ----------
        #pragma unroll
        for (int ct = 0; ct < 8; ++ct) {
            const int jrow = (ct << 4) + m;
            const vi4 wf0 = *(const vi4*)&wsign[0][jrow][quad * 16];
            const vi4 wf1 = *(const vi4*)&wsign[0][jrow][64 + quad * 16];
            const vi4 wc0 = *(const vi4*)&wsign[1][jrow][quad * 16];
            const vi4 wc1 = *(const vi4*)&wsign[1][jrow][64 + quad * 16];
            const vi4 wg0 = *(const vi4*)&wsign[2][jrow][quad * 16];
            const vi4 wg1 = *(const vi4*)&wsign[2][jrow][64 + quad * 16];
            const vi4 z = { 0, 0, 0, 0 };

            vi4 accF = __builtin_amdgcn_mfma_i32_16x16x64_i8(a0, wf0, z, 0, 0, 0);
            accF     = __builtin_amdgcn_mfma_i32_16x16x64_i8(a1, wf1, accF, 0, 0, 0);
            vi4 accC = __builtin_amdgcn_mfma_i32_16x16x64_i8(a0, wc0, z, 0, 0, 0);
            accC     = __builtin_amdgcn_mfma_i32_16x16x64_i8(a1, wc1, accC, 0, 0, 0);
            vi4 accG = __builtin_amdgcn_mfma_i32_16x16x64_i8(a0, wg0, z, 0, 0, 0);
            accG     = __builtin_amdgcn_mfma_i32_16x16x64_i8(a1, wg1, accG, 0, 0, 0);

            // ---------- epilogue: C/D layout col = m, row = quad*4 + r ----------
            const long long cbase = (long long)(row0 + quad * 4) * 128 + (ct << 4) + m;
            #pragma unroll
            for (int r = 0; r < 4; ++r) {
                const long long addr = cbase + (long long)r * 128;
                const float hp = hprev[addr];
                const float iv = invr[r];
                const float fv = sigmoidf_((float)accF[r] * iv + bfv[ct]);
                const float cx = (float)accC[r] * iv + bcv[ct];
                const float cv = cx * sigmoidf_(cx);               // silu
                const float gv = sigmoidf_((float)accG[r] * iv + bgv[ct]);
                const float hv = fv * hp + (1.0f - fv) * cv;
                out[addr]        = gv * hv;                        // o_t
                out[hoff + addr] = hv;                             // h_t
            }
        }
    }
}

extern "C" void kernel_launch(void* const* d_in, const int* in_sizes, int n_in,
                              void* d_out, int out_size, void* d_ws, size_t ws_size,
                              hipStream_t stream) {
    const float* x  = (const float*)d_in[0];
    const float* h  = (const float*)d_in[1];
    const float* Wf = (const float*)d_in[2];
    const float* Wc = (const float*)d_in[3];
    const float* Wg = (const float*)d_in[4];
    const float* bf = (const float*)d_in[5];
    const float* bc = (const float*)d_in[6];
    const float* bg = (const float*)d_in[7];
    float* out = (float*)d_out;
    const int nrows = in_sizes[0] / 128;   // B

    // 512 blocks x 8 waves = 4096 waves; 16384 groups -> 4 groups/wave;
    // 2 blocks/CU (54KB LDS) x 256 CU = 512 blocks exactly resident.
    hipLaunchKernelGGL(mlgru_kernel, dim3(512), dim3(THREADS), 0, stream,
                       x, h, Wf, Wc, Wg, bf, bc, bg, out, nrows);
}